// Round 1
// baseline (331.289 us; speedup 1.0000x reference)
//
#include <hip/hip_runtime.h>

#define NN 50000
#define TOPK 32
#define IN_C 128
#define OUT_C 64
#define NEG_SLOPE 0.2f
#define BN_EPS 1e-5f

// K1: MFMA, 16 nodes per block
#define K1_BLOCKS (NN / 16)         // 3125
// K2: 64-thread blocks, 1 wave = 8 nodes (8 lanes x 16B = full row)
#define K2_BLOCKS (NN / 8)          // 6250

// workspace layout (floats)
#define WS_XBF   0                       // bf16 x_lin: NN*64*2B
#define WS_AI    (NN * 32)
#define WS_AJ    (WS_AI + NN)
#define WS_SUMS  (WS_AJ + NN)            // 8 replicas x 128

typedef __bf16 bf16x8 __attribute__((ext_vector_type(8)));
typedef float f32x4 __attribute__((ext_vector_type(4)));
union BF8 { unsigned p[4]; bf16x8 v; };

__device__ inline float leaky(float a) { return a >= 0.f ? a : NEG_SLOPE * a; }
__device__ inline float bl(unsigned u) { return __uint_as_float(u << 16); }
__device__ inline float bh(unsigned u) { return __uint_as_float(u & 0xffff0000u); }

// fp32 -> bf16 via compiler cast (lowers to v_cvt_pk_bf16_f32, RNE — same
// rounding as the old manual sequence, ~5x fewer VALU ops)
__device__ inline unsigned pk2bf(float lo, float hi) {
    union { __bf16 b[2]; unsigned u; } cv;
    cv.b[0] = (__bf16)lo; cv.b[1] = (__bf16)hi;
    return cv.u;
}
__device__ inline unsigned short f2bf(float f) {
    union { __bf16 b; unsigned short u; } cv;
    cv.b = (__bf16)f;
    return cv.u;
}

// K1: x_lin(bf16) = x @ lin_w^T via MFMA 16x16x32_bf16 + a_i/a_j epilogue.
__global__ __launch_bounds__(256) void k1_mfma(
    const float* __restrict__ x, const float* __restrict__ emb,
    const float* __restrict__ lin_w,
    const float* __restrict__ att_i, const float* __restrict__ att_j,
    const float* __restrict__ att_em_i, const float* __restrict__ att_em_j,
    unsigned short* __restrict__ x_bf, float* __restrict__ a_i,
    float* __restrict__ a_j, float* __restrict__ sums)
{
    __shared__ float redi[16][5], redj[16][5];
    __shared__ float eredi[16][17], eredj[16][17];
    const int tid = threadIdx.x;
    if (blockIdx.x == 0) {
#pragma unroll
        for (int i = 0; i < 4; ++i) sums[tid + i * 256] = 0.f;
    }

    const int lane = tid & 63;
    const int wv = tid >> 6;
    const int quad = lane >> 4;
    const int nn = lane & 15;
    const int base = blockIdx.x * 16;
    const int c = wv * 16 + nn;          // this lane's output channel

    BF8 bfr[4], afr[4];
    {
        const float* wr = lin_w + (size_t)c * IN_C + quad * 8;
        const float* xr = x + (size_t)(base + nn) * IN_C + quad * 8;
#pragma unroll
        for (int s = 0; s < 4; ++s) {
            const float4 wa = *(const float4*)(wr + s * 32);
            const float4 wb = *(const float4*)(wr + s * 32 + 4);
            const float4 xa = *(const float4*)(xr + s * 32);
            const float4 xb = *(const float4*)(xr + s * 32 + 4);
            bfr[s].p[0] = pk2bf(wa.x, wa.y);
            bfr[s].p[1] = pk2bf(wa.z, wa.w);
            bfr[s].p[2] = pk2bf(wb.x, wb.y);
            bfr[s].p[3] = pk2bf(wb.z, wb.w);
            afr[s].p[0] = pk2bf(xa.x, xa.y);
            afr[s].p[1] = pk2bf(xa.z, xa.w);
            afr[s].p[2] = pk2bf(xb.x, xb.y);
            afr[s].p[3] = pk2bf(xb.z, xb.w);
        }
    }

    f32x4 acc = {0.f, 0.f, 0.f, 0.f};
#pragma unroll
    for (int s = 0; s < 4; ++s)
        acc = __builtin_amdgcn_mfma_f32_16x16x32_bf16(afr[s].v, bfr[s].v, acc,
                                                      0, 0, 0);

    const float aic = att_i[c], ajc = att_j[c];
    float pi[4], pj[4];
#pragma unroll
    for (int r = 0; r < 4; ++r) {
        const int node = base + quad * 4 + r;
        x_bf[(size_t)node * OUT_C + c] = f2bf(acc[r]);
        pi[r] = acc[r] * aic;
        pj[r] = acc[r] * ajc;
    }
#pragma unroll
    for (int d = 1; d < 16; d <<= 1) {
#pragma unroll
        for (int r = 0; r < 4; ++r) {
            pi[r] += __shfl_xor(pi[r], d, 64);
            pj[r] += __shfl_xor(pj[r], d, 64);
        }
    }
    if (nn == 0) {
#pragma unroll
        for (int r = 0; r < 4; ++r) {
            redi[quad * 4 + r][wv] = pi[r];
            redj[quad * 4 + r][wv] = pj[r];
        }
    }
    {
        const int nl = tid >> 4, c4 = tid & 15;
        const float4 e4 = ((const float4*)emb)[(size_t)(base + nl) * 16 + c4];
        const float4 i4 = ((const float4*)att_em_i)[c4];
        const float4 j4 = ((const float4*)att_em_j)[c4];
        eredi[nl][c4] = e4.x * i4.x + e4.y * i4.y + e4.z * i4.z + e4.w * i4.w;
        eredj[nl][c4] = e4.x * j4.x + e4.y * j4.y + e4.z * j4.z + e4.w * j4.w;
    }
    __syncthreads();
    if (tid < 16) {
        float si = redi[tid][0] + redi[tid][1] + redi[tid][2] + redi[tid][3];
        float sj = redj[tid][0] + redj[tid][1] + redj[tid][2] + redj[tid][3];
#pragma unroll
        for (int r = 0; r < 16; ++r) { si += eredi[tid][r]; sj += eredj[tid][r]; }
        a_i[base + tid] = si;
        a_j[base + tid] = sj;
    }
}

// per-edge accumulate: row u (8 bf16 channels) * weight w into A[8]
__device__ inline void accr(float* A, const uint4 u, const float w) {
    A[0] = fmaf(w, bl(u.x), A[0]); A[1] = fmaf(w, bh(u.x), A[1]);
    A[2] = fmaf(w, bl(u.y), A[2]); A[3] = fmaf(w, bh(u.y), A[3]);
    A[4] = fmaf(w, bl(u.z), A[4]); A[5] = fmaf(w, bh(u.z), A[5]);
    A[6] = fmaf(w, bl(u.w), A[6]); A[7] = fmaf(w, bh(u.w), A[7]);
}

// K2 v2: register-gather, zero LDS, no barriers.
// One wave per block, 8 nodes per wave (lane = g*8+q: node g, 16B row slice
// q = channels q*8..q*8+7). x_bf (6.4 MB) is L2/L3-resident, so LDS staging
// was pure overhead AND capped occupancy at 1 wave/SIMD (39.5 KB/block).
// Now: edges gathered in 4-edge batches into a triple-buffered register
// window (12 rows in flight); src indices and softmax weights broadcast
// within each 8-lane node group via shfl; BN partials shfl-reduced.
// launch_bounds(64,4): pin VGPR <= 128 -> 4 waves/SIMD (WG/CU-limited 16).
__global__ __launch_bounds__(64, 4) void k2_attn(
    const int* __restrict__ src, const uint4* __restrict__ x_bf4,
    const float* __restrict__ a_j, const float* __restrict__ a_i,
    const float* __restrict__ bias, float* __restrict__ out,
    float* __restrict__ sums)
{
    const int tid = threadIdx.x;         // == lane (64-thread block)
    const int g = tid >> 3;              // node within group of 8
    const int q = tid & 7;               // row slice
    const int gb = tid & 56;             // g*8 = first lane of this group
    const int t = blockIdx.x * 8 + g;

    // lane q owns softmax partition edges q*4..q*4+3 of its node
    const int4 sq = ((const int4*)(src + (size_t)t * TOPK))[q];
    const uint4 rs = x_bf4[(size_t)t * 8 + q];   // self row, issued early

    // batch b = edges 4b..4b+3; indices live in lane gb+b's sq
#define LOADB(dst, b) do {                                                  \
        const int i0_ = __shfl(sq.x, gb + (b), 64);                         \
        const int i1_ = __shfl(sq.y, gb + (b), 64);                         \
        const int i2_ = __shfl(sq.z, gb + (b), 64);                         \
        const int i3_ = __shfl(sq.w, gb + (b), 64);                         \
        dst[0] = x_bf4[(size_t)i0_ * 8 + q];                                \
        dst[1] = x_bf4[(size_t)i1_ * 8 + q];                                \
        dst[2] = x_bf4[(size_t)i2_ * 8 + q];                                \
        dst[3] = x_bf4[(size_t)i3_ * 8 + q];                                \
    } while (0)

    uint4 rA[4], rB[4], rC[4];
    LOADB(rA, 0); LOADB(rB, 1); LOADB(rC, 2);   // 12 rows in flight

    // softmax over 33 edges (overlaps the in-flight gathers)
    const float ai_t = a_i[t];
    float l0 = leaky(ai_t + a_j[sq.x]);
    float l1 = leaky(ai_t + a_j[sq.y]);
    float l2 = leaky(ai_t + a_j[sq.z]);
    float l3 = leaky(ai_t + a_j[sq.w]);
    const float ls = leaky(ai_t + a_j[t]);
    float mx = fmaxf(fmaxf(l0, l1), fmaxf(l2, l3));
#pragma unroll
    for (int d = 1; d < 8; d <<= 1) mx = fmaxf(mx, __shfl_xor(mx, d, 64));
    mx = fmaxf(mx, ls);
    const float e0 = __expf(l0 - mx), e1 = __expf(l1 - mx);
    const float e2 = __expf(l2 - mx), e3 = __expf(l3 - mx);
    const float es = __expf(ls - mx);
    float den = (e0 + e1) + (e2 + e3);
#pragma unroll
    for (int d = 1; d < 8; d <<= 1) den += __shfl_xor(den, d, 64);
    den += es + 1e-16f;
    const float inv = 1.f / den;
    const float w0 = e0 * inv, w1 = e1 * inv, w2 = e2 * inv, w3 = e3 * inv;
    const float wself = es * inv;        // lane-uniform within group

    float A[8];
#pragma unroll
    for (int j = 0; j < 8; ++j) A[j] = 0.f;

    // weight for edge 4b+k lives in lane gb+b's w{k}
#define ACCB(r, b) do {                                                     \
        const float wx_ = __shfl(w0, gb + (b), 64);                         \
        const float wy_ = __shfl(w1, gb + (b), 64);                         \
        const float wz_ = __shfl(w2, gb + (b), 64);                         \
        const float ww_ = __shfl(w3, gb + (b), 64);                         \
        accr(A, (r)[0], wx_); accr(A, (r)[1], wy_);                         \
        accr(A, (r)[2], wz_); accr(A, (r)[3], ww_);                         \
    } while (0)

    ACCB(rA, 0); LOADB(rA, 3);
    ACCB(rB, 1); LOADB(rB, 4);
    ACCB(rC, 2); LOADB(rC, 5);
    ACCB(rA, 3); LOADB(rA, 6);
    ACCB(rB, 4); LOADB(rB, 7);
    ACCB(rC, 5);
    ACCB(rA, 6);
    ACCB(rB, 7);
    accr(A, rs, wself);                  // self loop

    const float4 b0 = ((const float4*)bias)[q * 2];
    const float4 b1 = ((const float4*)bias)[q * 2 + 1];
    float v[8];
    v[0] = A[0] + b0.x; v[1] = A[1] + b0.y; v[2] = A[2] + b0.z; v[3] = A[3] + b0.w;
    v[4] = A[4] + b1.x; v[5] = A[5] + b1.y; v[6] = A[6] + b1.z; v[7] = A[7] + b1.w;
    float4* o4 = (float4*)(out + (size_t)t * OUT_C + q * 8);
    o4[0] = make_float4(v[0], v[1], v[2], v[3]);
    o4[1] = make_float4(v[4], v[5], v[6], v[7]);

    // BN partials: reduce over the wave's 8 nodes (g axis = lane bits 3..5)
    float s1[8], s2[8];
#pragma unroll
    for (int j = 0; j < 8; ++j) { s1[j] = v[j]; s2[j] = v[j] * v[j]; }
#pragma unroll
    for (int d = 8; d < 64; d <<= 1) {
#pragma unroll
        for (int j = 0; j < 8; ++j) {
            s1[j] += __shfl_xor(s1[j], d, 64);
            s2[j] += __shfl_xor(s2[j], d, 64);
        }
    }
    if (tid < 8) {                       // lane q=tid holds channels tid*8+j
        float* rep = sums + (blockIdx.x & 7) * 128;
#pragma unroll
        for (int j = 0; j < 8; ++j) {
            atomicAdd(&rep[tid * 8 + j], s1[j]);
            atomicAdd(&rep[64 + tid * 8 + j], s2[j]);
        }
    }
#undef LOADB
#undef ACCB
}

// K4: BN stats from the 8 sum replicas (redundant per block), apply + ReLU.
__global__ __launch_bounds__(256) void k4_bn(
    float* __restrict__ out, const float* __restrict__ sums,
    const float* __restrict__ gamma, const float* __restrict__ beta)
{
    __shared__ float s_sc[64], s_sh[64];
    const int tid = threadIdx.x;
    if (tid < 64) {
        float s1 = 0.f, s2 = 0.f;
#pragma unroll
        for (int r = 0; r < 8; ++r) {
            s1 += sums[r * 128 + tid];
            s2 += sums[r * 128 + 64 + tid];
        }
        const float mu = s1 / (float)NN;
        const float ex2 = s2 / (float)NN;
        const float var = fmaxf(ex2 - mu * mu, 0.f);
        const float sc = gamma[tid] / sqrtf(var + BN_EPS);
        s_sc[tid] = sc;
        s_sh[tid] = beta[tid] - mu * sc;
    }
    __syncthreads();
    const int total = NN * OUT_C / 4;
    float4* p = (float4*)out;
    for (int idx = blockIdx.x * 256 + tid; idx < total; idx += gridDim.x * 256) {
        float4 v = p[idx];
        const int c0 = (idx & 15) * 4;
        v.x = fmaxf(fmaf(v.x, s_sc[c0 + 0], s_sh[c0 + 0]), 0.f);
        v.y = fmaxf(fmaf(v.y, s_sc[c0 + 1], s_sh[c0 + 1]), 0.f);
        v.z = fmaxf(fmaf(v.z, s_sc[c0 + 2], s_sh[c0 + 2]), 0.f);
        v.w = fmaxf(fmaf(v.w, s_sc[c0 + 3], s_sh[c0 + 3]), 0.f);
        p[idx] = v;
    }
}

extern "C" void kernel_launch(void* const* d_in, const int* in_sizes, int n_in,
                              void* d_out, int out_size, void* d_ws, size_t ws_size,
                              hipStream_t stream) {
    const float* x        = (const float*)d_in[0];
    const float* emb      = (const float*)d_in[1];
    const int*   edge     = (const int*)d_in[2];   // row 0 = src
    const float* lin_w    = (const float*)d_in[3];
    const float* att_i    = (const float*)d_in[4];
    const float* att_j    = (const float*)d_in[5];
    const float* att_em_i = (const float*)d_in[6];
    const float* att_em_j = (const float*)d_in[7];
    const float* bias     = (const float*)d_in[8];
    const float* gamma    = (const float*)d_in[9];
    const float* beta     = (const float*)d_in[10];

    float* ws    = (float*)d_ws;
    unsigned short* x_bf = (unsigned short*)(ws + WS_XBF);
    float* a_i   = ws + WS_AI;
    float* a_j   = ws + WS_AJ;
    float* sums  = ws + WS_SUMS;
    float* out   = (float*)d_out;

    k1_mfma<<<K1_BLOCKS, 256, 0, stream>>>(x, emb, lin_w, att_i, att_j,
                                           att_em_i, att_em_j, x_bf, a_i, a_j, sums);
    k2_attn<<<K2_BLOCKS, 64, 0, stream>>>(edge, (const uint4*)x_bf, a_j, a_i,
                                          bias, out, sums);
    k4_bn<<<1024, 256, 0, stream>>>(out, sums, gamma, beta);
}

// Round 2
// 297.052 us; speedup vs baseline: 1.1153x; 1.1153x over previous
//
#include <hip/hip_runtime.h>

#define NN 50000
#define TOPK 32
#define IN_C 128
#define OUT_C 64
#define NEG_SLOPE 0.2f
#define BN_EPS 1e-5f

// K1: MFMA, 16 nodes per block
#define K1_BLOCKS (NN / 16)         // 3125
// K2: 64-thread blocks, 1 wave = 8 nodes (8 lanes x 16B = full row)
#define K2_BLOCKS (NN / 8)          // 6250

// workspace layout (floats)
#define WS_XBF   0                       // bf16 x_lin: NN*64*2B
#define WS_AI    (NN * 32)
#define WS_AJ    (WS_AI + NN)
#define WS_SUMS  (WS_AJ + NN)            // 8 replicas x 128

typedef __bf16 bf16x8 __attribute__((ext_vector_type(8)));
typedef float f32x4 __attribute__((ext_vector_type(4)));
union BF8 { unsigned p[4]; bf16x8 v; };

__device__ inline float leaky(float a) { return a >= 0.f ? a : NEG_SLOPE * a; }
__device__ inline float bl(unsigned u) { return __uint_as_float(u << 16); }
__device__ inline float bh(unsigned u) { return __uint_as_float(u & 0xffff0000u); }

// fp32 -> bf16 via compiler cast (lowers to v_cvt_pk_bf16_f32, RNE)
__device__ inline unsigned pk2bf(float lo, float hi) {
    union { __bf16 b[2]; unsigned u; } cv;
    cv.b[0] = (__bf16)lo; cv.b[1] = (__bf16)hi;
    return cv.u;
}
__device__ inline unsigned short f2bf(float f) {
    union { __bf16 b; unsigned short u; } cv;
    cv.b = (__bf16)f;
    return cv.u;
}

// K1: x_lin(bf16) = x @ lin_w^T via MFMA 16x16x32_bf16 + a_i/a_j epilogue.
__global__ __launch_bounds__(256) void k1_mfma(
    const float* __restrict__ x, const float* __restrict__ emb,
    const float* __restrict__ lin_w,
    const float* __restrict__ att_i, const float* __restrict__ att_j,
    const float* __restrict__ att_em_i, const float* __restrict__ att_em_j,
    unsigned short* __restrict__ x_bf, float* __restrict__ a_i,
    float* __restrict__ a_j, float* __restrict__ sums)
{
    __shared__ float redi[16][5], redj[16][5];
    __shared__ float eredi[16][17], eredj[16][17];
    const int tid = threadIdx.x;
    if (blockIdx.x == 0) {
#pragma unroll
        for (int i = 0; i < 4; ++i) sums[tid + i * 256] = 0.f;
    }

    const int lane = tid & 63;
    const int wv = tid >> 6;
    const int quad = lane >> 4;
    const int nn = lane & 15;
    const int base = blockIdx.x * 16;
    const int c = wv * 16 + nn;          // this lane's output channel

    BF8 bfr[4], afr[4];
    {
        const float* wr = lin_w + (size_t)c * IN_C + quad * 8;
        const float* xr = x + (size_t)(base + nn) * IN_C + quad * 8;
#pragma unroll
        for (int s = 0; s < 4; ++s) {
            const float4 wa = *(const float4*)(wr + s * 32);
            const float4 wb = *(const float4*)(wr + s * 32 + 4);
            const float4 xa = *(const float4*)(xr + s * 32);
            const float4 xb = *(const float4*)(xr + s * 32 + 4);
            bfr[s].p[0] = pk2bf(wa.x, wa.y);
            bfr[s].p[1] = pk2bf(wa.z, wa.w);
            bfr[s].p[2] = pk2bf(wb.x, wb.y);
            bfr[s].p[3] = pk2bf(wb.z, wb.w);
            afr[s].p[0] = pk2bf(xa.x, xa.y);
            afr[s].p[1] = pk2bf(xa.z, xa.w);
            afr[s].p[2] = pk2bf(xb.x, xb.y);
            afr[s].p[3] = pk2bf(xb.z, xb.w);
        }
    }

    f32x4 acc = {0.f, 0.f, 0.f, 0.f};
#pragma unroll
    for (int s = 0; s < 4; ++s)
        acc = __builtin_amdgcn_mfma_f32_16x16x32_bf16(afr[s].v, bfr[s].v, acc,
                                                      0, 0, 0);

    const float aic = att_i[c], ajc = att_j[c];
    float pi[4], pj[4];
#pragma unroll
    for (int r = 0; r < 4; ++r) {
        const int node = base + quad * 4 + r;
        x_bf[(size_t)node * OUT_C + c] = f2bf(acc[r]);
        pi[r] = acc[r] * aic;
        pj[r] = acc[r] * ajc;
    }
#pragma unroll
    for (int d = 1; d < 16; d <<= 1) {
#pragma unroll
        for (int r = 0; r < 4; ++r) {
            pi[r] += __shfl_xor(pi[r], d, 64);
            pj[r] += __shfl_xor(pj[r], d, 64);
        }
    }
    if (nn == 0) {
#pragma unroll
        for (int r = 0; r < 4; ++r) {
            redi[quad * 4 + r][wv] = pi[r];
            redj[quad * 4 + r][wv] = pj[r];
        }
    }
    {
        const int nl = tid >> 4, c4 = tid & 15;
        const float4 e4 = ((const float4*)emb)[(size_t)(base + nl) * 16 + c4];
        const float4 i4 = ((const float4*)att_em_i)[c4];
        const float4 j4 = ((const float4*)att_em_j)[c4];
        eredi[nl][c4] = e4.x * i4.x + e4.y * i4.y + e4.z * i4.z + e4.w * i4.w;
        eredj[nl][c4] = e4.x * j4.x + e4.y * j4.y + e4.z * j4.z + e4.w * j4.w;
    }
    __syncthreads();
    if (tid < 16) {
        float si = redi[tid][0] + redi[tid][1] + redi[tid][2] + redi[tid][3];
        float sj = redj[tid][0] + redj[tid][1] + redj[tid][2] + redj[tid][3];
#pragma unroll
        for (int r = 0; r < 16; ++r) { si += eredi[tid][r]; sj += eredj[tid][r]; }
        a_i[base + tid] = si;
        a_j[base + tid] = sj;
    }
}

// per-edge accumulate: row u (8 bf16 channels) * weight w into A[8]
__device__ inline void accr(float* A, const uint4 u, const float w) {
    A[0] = fmaf(w, bl(u.x), A[0]); A[1] = fmaf(w, bh(u.x), A[1]);
    A[2] = fmaf(w, bl(u.y), A[2]); A[3] = fmaf(w, bh(u.y), A[3]);
    A[4] = fmaf(w, bl(u.z), A[4]); A[5] = fmaf(w, bh(u.z), A[5]);
    A[6] = fmaf(w, bl(u.w), A[6]); A[7] = fmaf(w, bh(u.w), A[7]);
}

// K2 v3: register-gather, zero LDS, no barriers.
// R1 post-mortem: __launch_bounds__(64,4) capped VGPR at 64 -> ~90 live regs
// spilled to scratch (WRITE_SIZE 150 MB vs 12.8 MB ideal, VALUBusy 0.15%).
// Fix: no min-waves hint; demand ~100 VGPR stays in the <=128 occupancy tier
// (4 waves/SIMD, 16 single-wave blocks/CU). Pipeline unchanged: 3x4-edge
// register buffers (12 rows in flight), shfl-broadcast indices/weights,
// shfl-reduced BN partials.
__global__ __launch_bounds__(64) void k2_attn(
    const int* __restrict__ src, const uint4* __restrict__ x_bf4,
    const float* __restrict__ a_j, const float* __restrict__ a_i,
    const float* __restrict__ bias, float* __restrict__ out,
    float* __restrict__ sums)
{
    const int tid = threadIdx.x;         // == lane (64-thread block)
    const int g = tid >> 3;              // node within group of 8
    const int q = tid & 7;               // row slice
    const int gb = tid & 56;             // g*8 = first lane of this group
    const int t = blockIdx.x * 8 + g;

    // lane q owns softmax partition edges q*4..q*4+3 of its node
    const int4 sq = ((const int4*)(src + (size_t)t * TOPK))[q];
    const uint4 rs = x_bf4[(size_t)t * 8 + q];   // self row, issued early

    // batch b = edges 4b..4b+3; indices live in lane gb+b's sq
#define LOADB(dst, b) do {                                                  \
        const int i0_ = __shfl(sq.x, gb + (b), 64);                         \
        const int i1_ = __shfl(sq.y, gb + (b), 64);                         \
        const int i2_ = __shfl(sq.z, gb + (b), 64);                         \
        const int i3_ = __shfl(sq.w, gb + (b), 64);                         \
        dst[0] = x_bf4[(size_t)i0_ * 8 + q];                                \
        dst[1] = x_bf4[(size_t)i1_ * 8 + q];                                \
        dst[2] = x_bf4[(size_t)i2_ * 8 + q];                                \
        dst[3] = x_bf4[(size_t)i3_ * 8 + q];                                \
    } while (0)

    uint4 rA[4], rB[4], rC[4];
    LOADB(rA, 0); LOADB(rB, 1); LOADB(rC, 2);   // 12 rows in flight

    // softmax over 33 edges (overlaps the in-flight gathers)
    const float ai_t = a_i[t];
    float l0 = leaky(ai_t + a_j[sq.x]);
    float l1 = leaky(ai_t + a_j[sq.y]);
    float l2 = leaky(ai_t + a_j[sq.z]);
    float l3 = leaky(ai_t + a_j[sq.w]);
    const float ls = leaky(ai_t + a_j[t]);
    float mx = fmaxf(fmaxf(l0, l1), fmaxf(l2, l3));
#pragma unroll
    for (int d = 1; d < 8; d <<= 1) mx = fmaxf(mx, __shfl_xor(mx, d, 64));
    mx = fmaxf(mx, ls);
    const float e0 = __expf(l0 - mx), e1 = __expf(l1 - mx);
    const float e2 = __expf(l2 - mx), e3 = __expf(l3 - mx);
    const float es = __expf(ls - mx);
    float den = (e0 + e1) + (e2 + e3);
#pragma unroll
    for (int d = 1; d < 8; d <<= 1) den += __shfl_xor(den, d, 64);
    den += es + 1e-16f;
    const float inv = 1.f / den;
    const float w0 = e0 * inv, w1 = e1 * inv, w2 = e2 * inv, w3 = e3 * inv;
    const float wself = es * inv;        // lane-uniform within group

    float A[8];
#pragma unroll
    for (int j = 0; j < 8; ++j) A[j] = 0.f;

    // weight for edge 4b+k lives in lane gb+b's w{k}
#define ACCB(r, b) do {                                                     \
        const float wx_ = __shfl(w0, gb + (b), 64);                         \
        const float wy_ = __shfl(w1, gb + (b), 64);                         \
        const float wz_ = __shfl(w2, gb + (b), 64);                         \
        const float ww_ = __shfl(w3, gb + (b), 64);                         \
        accr(A, (r)[0], wx_); accr(A, (r)[1], wy_);                         \
        accr(A, (r)[2], wz_); accr(A, (r)[3], ww_);                         \
    } while (0)

    ACCB(rA, 0); LOADB(rA, 3);
    ACCB(rB, 1); LOADB(rB, 4);
    ACCB(rC, 2); LOADB(rC, 5);
    ACCB(rA, 3); LOADB(rA, 6);
    ACCB(rB, 4); LOADB(rB, 7);
    ACCB(rC, 5);
    ACCB(rA, 6);
    ACCB(rB, 7);
    accr(A, rs, wself);                  // self loop

    const float4 b0 = ((const float4*)bias)[q * 2];
    const float4 b1 = ((const float4*)bias)[q * 2 + 1];
    float v[8];
    v[0] = A[0] + b0.x; v[1] = A[1] + b0.y; v[2] = A[2] + b0.z; v[3] = A[3] + b0.w;
    v[4] = A[4] + b1.x; v[5] = A[5] + b1.y; v[6] = A[6] + b1.z; v[7] = A[7] + b1.w;
    float4* o4 = (float4*)(out + (size_t)t * OUT_C + q * 8);
    o4[0] = make_float4(v[0], v[1], v[2], v[3]);
    o4[1] = make_float4(v[4], v[5], v[6], v[7]);

    // BN partials: reduce over the wave's 8 nodes (g axis = lane bits 3..5)
    float s1[8], s2[8];
#pragma unroll
    for (int j = 0; j < 8; ++j) { s1[j] = v[j]; s2[j] = v[j] * v[j]; }
#pragma unroll
    for (int d = 8; d < 64; d <<= 1) {
#pragma unroll
        for (int j = 0; j < 8; ++j) {
            s1[j] += __shfl_xor(s1[j], d, 64);
            s2[j] += __shfl_xor(s2[j], d, 64);
        }
    }
    if (tid < 8) {                       // lane q=tid holds channels tid*8+j
        float* rep = sums + (blockIdx.x & 7) * 128;
#pragma unroll
        for (int j = 0; j < 8; ++j) {
            atomicAdd(&rep[tid * 8 + j], s1[j]);
            atomicAdd(&rep[64 + tid * 8 + j], s2[j]);
        }
    }
#undef LOADB
#undef ACCB
}

// K4: BN stats from the 8 sum replicas (redundant per block), apply + ReLU.
__global__ __launch_bounds__(256) void k4_bn(
    float* __restrict__ out, const float* __restrict__ sums,
    const float* __restrict__ gamma, const float* __restrict__ beta)
{
    __shared__ float s_sc[64], s_sh[64];
    const int tid = threadIdx.x;
    if (tid < 64) {
        float s1 = 0.f, s2 = 0.f;
#pragma unroll
        for (int r = 0; r < 8; ++r) {
            s1 += sums[r * 128 + tid];
            s2 += sums[r * 128 + 64 + tid];
        }
        const float mu = s1 / (float)NN;
        const float ex2 = s2 / (float)NN;
        const float var = fmaxf(ex2 - mu * mu, 0.f);
        const float sc = gamma[tid] / sqrtf(var + BN_EPS);
        s_sc[tid] = sc;
        s_sh[tid] = beta[tid] - mu * sc;
    }
    __syncthreads();
    const int total = NN * OUT_C / 4;
    float4* p = (float4*)out;
    for (int idx = blockIdx.x * 256 + tid; idx < total; idx += gridDim.x * 256) {
        float4 v = p[idx];
        const int c0 = (idx & 15) * 4;
        v.x = fmaxf(fmaf(v.x, s_sc[c0 + 0], s_sh[c0 + 0]), 0.f);
        v.y = fmaxf(fmaf(v.y, s_sc[c0 + 1], s_sh[c0 + 1]), 0.f);
        v.z = fmaxf(fmaf(v.z, s_sc[c0 + 2], s_sh[c0 + 2]), 0.f);
        v.w = fmaxf(fmaf(v.w, s_sc[c0 + 3], s_sh[c0 + 3]), 0.f);
        p[idx] = v;
    }
}

extern "C" void kernel_launch(void* const* d_in, const int* in_sizes, int n_in,
                              void* d_out, int out_size, void* d_ws, size_t ws_size,
                              hipStream_t stream) {
    const float* x        = (const float*)d_in[0];
    const float* emb      = (const float*)d_in[1];
    const int*   edge     = (const int*)d_in[2];   // row 0 = src
    const float* lin_w    = (const float*)d_in[3];
    const float* att_i    = (const float*)d_in[4];
    const float* att_j    = (const float*)d_in[5];
    const float* att_em_i = (const float*)d_in[6];
    const float* att_em_j = (const float*)d_in[7];
    const float* bias     = (const float*)d_in[8];
    const float* gamma    = (const float*)d_in[9];
    const float* beta     = (const float*)d_in[10];

    float* ws    = (float*)d_ws;
    unsigned short* x_bf = (unsigned short*)(ws + WS_XBF);
    float* a_i   = ws + WS_AI;
    float* a_j   = ws + WS_AJ;
    float* sums  = ws + WS_SUMS;
    float* out   = (float*)d_out;

    k1_mfma<<<K1_BLOCKS, 256, 0, stream>>>(x, emb, lin_w, att_i, att_j,
                                           att_em_i, att_em_j, x_bf, a_i, a_j, sums);
    k2_attn<<<K2_BLOCKS, 64, 0, stream>>>(edge, (const uint4*)x_bf, a_j, a_i,
                                          bias, out, sums);
    k4_bn<<<1024, 256, 0, stream>>>(out, sums, gamma, beta);
}

// Round 3
// 291.656 us; speedup vs baseline: 1.1359x; 1.0185x over previous
//
#include <hip/hip_runtime.h>

#define NN 50000
#define TOPK 32
#define IN_C 128
#define OUT_C 64
#define NEG_SLOPE 0.2f
#define BN_EPS 1e-5f

// K1: MFMA, 16 nodes per block
#define K1_BLOCKS (NN / 16)         // 3125
// K2: 64-thread blocks, 1 wave = 8 nodes (8 lanes x 16B = full row)
#define K2_BLOCKS (NN / 8)          // 6250
#define STAGED 20                   // edges 0..19 staged in LDS (20 KB)

// workspace layout (floats)
#define WS_XBF   0                       // bf16 x_lin: NN*64*2B
#define WS_AI    (NN * 32)
#define WS_AJ    (WS_AI + NN)
#define WS_SUMS  (WS_AJ + NN)            // 8 replicas x 128

typedef __bf16 bf16x8 __attribute__((ext_vector_type(8)));
typedef float f32x4 __attribute__((ext_vector_type(4)));
union BF8 { unsigned p[4]; bf16x8 v; };

__device__ inline float leaky(float a) { return a >= 0.f ? a : NEG_SLOPE * a; }
__device__ inline float bl(unsigned u) { return __uint_as_float(u << 16); }
__device__ inline float bh(unsigned u) { return __uint_as_float(u & 0xffff0000u); }

// fp32 -> bf16 via compiler cast (lowers to v_cvt_pk_bf16_f32, RNE)
__device__ inline unsigned pk2bf(float lo, float hi) {
    union { __bf16 b[2]; unsigned u; } cv;
    cv.b[0] = (__bf16)lo; cv.b[1] = (__bf16)hi;
    return cv.u;
}
__device__ inline unsigned short f2bf(float f) {
    union { __bf16 b; unsigned short u; } cv;
    cv.b = (__bf16)f;
    return cv.u;
}

// async global->LDS, 16 B per lane; LDS dest = base + lane*16 (HW rule)
__device__ inline void async16(const uint4* g, uint4* l) {
    __builtin_amdgcn_global_load_lds(
        (const __attribute__((address_space(1))) void*)(const void*)g,
        (__attribute__((address_space(3))) void*)(void*)l, 16, 0, 0);
}

// K1: x_lin(bf16) = x @ lin_w^T via MFMA 16x16x32_bf16 + a_i/a_j epilogue.
__global__ __launch_bounds__(256) void k1_mfma(
    const float* __restrict__ x, const float* __restrict__ emb,
    const float* __restrict__ lin_w,
    const float* __restrict__ att_i, const float* __restrict__ att_j,
    const float* __restrict__ att_em_i, const float* __restrict__ att_em_j,
    unsigned short* __restrict__ x_bf, float* __restrict__ a_i,
    float* __restrict__ a_j, float* __restrict__ sums)
{
    __shared__ float redi[16][5], redj[16][5];
    __shared__ float eredi[16][17], eredj[16][17];
    const int tid = threadIdx.x;
    if (blockIdx.x == 0) {
#pragma unroll
        for (int i = 0; i < 4; ++i) sums[tid + i * 256] = 0.f;
    }

    const int lane = tid & 63;
    const int wv = tid >> 6;
    const int quad = lane >> 4;
    const int nn = lane & 15;
    const int base = blockIdx.x * 16;
    const int c = wv * 16 + nn;          // this lane's output channel

    BF8 bfr[4], afr[4];
    {
        const float* wr = lin_w + (size_t)c * IN_C + quad * 8;
        const float* xr = x + (size_t)(base + nn) * IN_C + quad * 8;
#pragma unroll
        for (int s = 0; s < 4; ++s) {
            const float4 wa = *(const float4*)(wr + s * 32);
            const float4 wb = *(const float4*)(wr + s * 32 + 4);
            const float4 xa = *(const float4*)(xr + s * 32);
            const float4 xb = *(const float4*)(xr + s * 32 + 4);
            bfr[s].p[0] = pk2bf(wa.x, wa.y);
            bfr[s].p[1] = pk2bf(wa.z, wa.w);
            bfr[s].p[2] = pk2bf(wb.x, wb.y);
            bfr[s].p[3] = pk2bf(wb.z, wb.w);
            afr[s].p[0] = pk2bf(xa.x, xa.y);
            afr[s].p[1] = pk2bf(xa.z, xa.w);
            afr[s].p[2] = pk2bf(xb.x, xb.y);
            afr[s].p[3] = pk2bf(xb.z, xb.w);
        }
    }

    f32x4 acc = {0.f, 0.f, 0.f, 0.f};
#pragma unroll
    for (int s = 0; s < 4; ++s)
        acc = __builtin_amdgcn_mfma_f32_16x16x32_bf16(afr[s].v, bfr[s].v, acc,
                                                      0, 0, 0);

    const float aic = att_i[c], ajc = att_j[c];
    float pi[4], pj[4];
#pragma unroll
    for (int r = 0; r < 4; ++r) {
        const int node = base + quad * 4 + r;
        x_bf[(size_t)node * OUT_C + c] = f2bf(acc[r]);
        pi[r] = acc[r] * aic;
        pj[r] = acc[r] * ajc;
    }
#pragma unroll
    for (int d = 1; d < 16; d <<= 1) {
#pragma unroll
        for (int r = 0; r < 4; ++r) {
            pi[r] += __shfl_xor(pi[r], d, 64);
            pj[r] += __shfl_xor(pj[r], d, 64);
        }
    }
    if (nn == 0) {
#pragma unroll
        for (int r = 0; r < 4; ++r) {
            redi[quad * 4 + r][wv] = pi[r];
            redj[quad * 4 + r][wv] = pj[r];
        }
    }
    {
        const int nl = tid >> 4, c4 = tid & 15;
        const float4 e4 = ((const float4*)emb)[(size_t)(base + nl) * 16 + c4];
        const float4 i4 = ((const float4*)att_em_i)[c4];
        const float4 j4 = ((const float4*)att_em_j)[c4];
        eredi[nl][c4] = e4.x * i4.x + e4.y * i4.y + e4.z * i4.z + e4.w * i4.w;
        eredj[nl][c4] = e4.x * j4.x + e4.y * j4.y + e4.z * j4.z + e4.w * j4.w;
    }
    __syncthreads();
    if (tid < 16) {
        float si = redi[tid][0] + redi[tid][1] + redi[tid][2] + redi[tid][3];
        float sj = redj[tid][0] + redj[tid][1] + redj[tid][2] + redj[tid][3];
#pragma unroll
        for (int r = 0; r < 16; ++r) { si += eredi[tid][r]; sj += eredj[tid][r]; }
        a_i[base + tid] = si;
        a_j[base + tid] = sj;
    }
}

// per-edge accumulate: row u (8 bf16 channels) * weight w into A[8]
__device__ inline void accr(float* A, const uint4 u, const float w) {
    A[0] = fmaf(w, bl(u.x), A[0]); A[1] = fmaf(w, bh(u.x), A[1]);
    A[2] = fmaf(w, bl(u.y), A[2]); A[3] = fmaf(w, bh(u.y), A[3]);
    A[4] = fmaf(w, bl(u.z), A[4]); A[5] = fmaf(w, bh(u.z), A[5]);
    A[6] = fmaf(w, bl(u.w), A[6]); A[7] = fmaf(w, bh(u.w), A[7]);
}

// K2 v4: back to round-0's issue-all/drain-once structure (33 gathers in
// flight per wave — the MLP engine; R2's 12-deep phase pipeline was 4x
// slower at VALUBusy 4%). Occupancy fix on top: stage only edges 0..19 in
// LDS (20 KB -> 8 blocks/CU = 2 waves/SIMD, vs round-0's 39.5 KB -> 1
// wave/SIMD); edges 20..31 + self to registers, ALL issued upfront.
// wbuf/sb1/sb2 replaced by shfl broadcast / shfl reduce (R1/R2-verified).
__global__ __launch_bounds__(64) void k2_attn(
    const int* __restrict__ src, const uint4* __restrict__ x_bf4,
    const float* __restrict__ a_j, const float* __restrict__ a_i,
    const float* __restrict__ bias, float* __restrict__ out,
    float* __restrict__ sums)
{
    __shared__ uint4 stage[STAGED * 64];  // 20 KB staged rows

    const int tid = threadIdx.x;         // == lane (64-thread block)
    const int g = tid >> 3;              // node within group of 8
    const int q = tid & 7;               // row slice
    const int gb = tid & 56;             // g*8 = first lane of this group
    const int t = blockIdx.x * 8 + g;

    // all 32 src indices of this lane's node (broadcast across its 8 lanes)
    const int4* sp4 = (const int4*)(src + (size_t)t * TOPK);
    int4 s4[8];
#pragma unroll
    for (int i = 0; i < 8; ++i) s4[i] = sp4[i];
    const int4 sq = s4[q];               // this lane's softmax partition

    // issue staged gathers: edge e=4i+c -> stage[e*64 + lane]
#pragma unroll
    for (int i = 0; i < STAGED / 4; ++i) {
        async16(x_bf4 + ((size_t)s4[i].x * 8 + q), &stage[(i * 4 + 0) * 64]);
        async16(x_bf4 + ((size_t)s4[i].y * 8 + q), &stage[(i * 4 + 1) * 64]);
        async16(x_bf4 + ((size_t)s4[i].z * 8 + q), &stage[(i * 4 + 2) * 64]);
        async16(x_bf4 + ((size_t)s4[i].w * 8 + q), &stage[(i * 4 + 3) * 64]);
    }

    // attention-logit inputs next (so softmax can wait at vmcnt(N) with the
    // register rows still in flight)
    const float ai_t = a_i[t];
    const float aj0 = a_j[sq.x], aj1 = a_j[sq.y];
    const float aj2 = a_j[sq.z], aj3 = a_j[sq.w];
    const float ajs = a_j[t];

    // register rows: edges 20..31 + self, issued upfront (issue-all pattern)
    uint4 r[12];
    r[0]  = x_bf4[(size_t)s4[5].x * 8 + q];
    r[1]  = x_bf4[(size_t)s4[5].y * 8 + q];
    r[2]  = x_bf4[(size_t)s4[5].z * 8 + q];
    r[3]  = x_bf4[(size_t)s4[5].w * 8 + q];
    r[4]  = x_bf4[(size_t)s4[6].x * 8 + q];
    r[5]  = x_bf4[(size_t)s4[6].y * 8 + q];
    r[6]  = x_bf4[(size_t)s4[6].z * 8 + q];
    r[7]  = x_bf4[(size_t)s4[6].w * 8 + q];
    r[8]  = x_bf4[(size_t)s4[7].x * 8 + q];
    r[9]  = x_bf4[(size_t)s4[7].y * 8 + q];
    r[10] = x_bf4[(size_t)s4[7].z * 8 + q];
    r[11] = x_bf4[(size_t)s4[7].w * 8 + q];
    const uint4 rs = x_bf4[(size_t)t * 8 + q];   // self row

    // softmax over 33 edges: lane q owns edges q*4..q*4+3
    float l0 = leaky(ai_t + aj0);
    float l1 = leaky(ai_t + aj1);
    float l2 = leaky(ai_t + aj2);
    float l3 = leaky(ai_t + aj3);
    const float ls = leaky(ai_t + ajs);
    float mx = fmaxf(fmaxf(l0, l1), fmaxf(l2, l3));
#pragma unroll
    for (int d = 1; d < 8; d <<= 1) mx = fmaxf(mx, __shfl_xor(mx, d, 64));
    mx = fmaxf(mx, ls);
    const float e0 = __expf(l0 - mx), e1 = __expf(l1 - mx);
    const float e2 = __expf(l2 - mx), e3 = __expf(l3 - mx);
    const float es = __expf(ls - mx);
    float den = (e0 + e1) + (e2 + e3);
#pragma unroll
    for (int d = 1; d < 8; d <<= 1) den += __shfl_xor(den, d, 64);
    den += es + 1e-16f;
    const float inv = 1.f / den;
    const float w0 = e0 * inv, w1 = e1 * inv, w2 = e2 * inv, w3 = e3 * inv;
    const float wself = es * inv;        // lane-uniform within group

    __builtin_amdgcn_s_waitcnt(0x0F70);  // vmcnt(0): staged + reg rows ready
    __syncthreads();

    float A[8];
#pragma unroll
    for (int j = 0; j < 8; ++j) A[j] = 0.f;

    // weight for edge 4b+k lives in lane gb+b's w{k}
#define WB(b) const float wx_ = __shfl(w0, gb + (b), 64);                   \
              const float wy_ = __shfl(w1, gb + (b), 64);                   \
              const float wz_ = __shfl(w2, gb + (b), 64);                   \
              const float ww_ = __shfl(w3, gb + (b), 64)

    // staged edges 0..19 (accumulation order preserved: e = 0..32)
#pragma unroll
    for (int b = 0; b < STAGED / 4; ++b) {
        WB(b);
        accr(A, stage[(b * 4 + 0) * 64 + tid], wx_);
        accr(A, stage[(b * 4 + 1) * 64 + tid], wy_);
        accr(A, stage[(b * 4 + 2) * 64 + tid], wz_);
        accr(A, stage[(b * 4 + 3) * 64 + tid], ww_);
    }
    // register edges 20..31
    { WB(5); accr(A, r[0], wx_); accr(A, r[1], wy_);
             accr(A, r[2], wz_); accr(A, r[3], ww_); }
    { WB(6); accr(A, r[4], wx_); accr(A, r[5], wy_);
             accr(A, r[6], wz_); accr(A, r[7], ww_); }
    { WB(7); accr(A, r[8], wx_); accr(A, r[9], wy_);
             accr(A, r[10], wz_); accr(A, r[11], ww_); }
    accr(A, rs, wself);                  // self loop
#undef WB

    const float4 b0 = ((const float4*)bias)[q * 2];
    const float4 b1 = ((const float4*)bias)[q * 2 + 1];
    float v[8];
    v[0] = A[0] + b0.x; v[1] = A[1] + b0.y; v[2] = A[2] + b0.z; v[3] = A[3] + b0.w;
    v[4] = A[4] + b1.x; v[5] = A[5] + b1.y; v[6] = A[6] + b1.z; v[7] = A[7] + b1.w;
    float4* o4 = (float4*)(out + (size_t)t * OUT_C + q * 8);
    o4[0] = make_float4(v[0], v[1], v[2], v[3]);
    o4[1] = make_float4(v[4], v[5], v[6], v[7]);

    // BN partials: reduce over the wave's 8 nodes (g axis = lane bits 3..5)
    float s1[8], s2[8];
#pragma unroll
    for (int j = 0; j < 8; ++j) { s1[j] = v[j]; s2[j] = v[j] * v[j]; }
#pragma unroll
    for (int d = 8; d < 64; d <<= 1) {
#pragma unroll
        for (int j = 0; j < 8; ++j) {
            s1[j] += __shfl_xor(s1[j], d, 64);
            s2[j] += __shfl_xor(s2[j], d, 64);
        }
    }
    if (tid < 8) {                       // lane q=tid holds channels tid*8+j
        float* rep = sums + (blockIdx.x & 7) * 128;
#pragma unroll
        for (int j = 0; j < 8; ++j) {
            atomicAdd(&rep[tid * 8 + j], s1[j]);
            atomicAdd(&rep[64 + tid * 8 + j], s2[j]);
        }
    }
}

// K4: BN stats from the 8 sum replicas (redundant per block), apply + ReLU.
__global__ __launch_bounds__(256) void k4_bn(
    float* __restrict__ out, const float* __restrict__ sums,
    const float* __restrict__ gamma, const float* __restrict__ beta)
{
    __shared__ float s_sc[64], s_sh[64];
    const int tid = threadIdx.x;
    if (tid < 64) {
        float s1 = 0.f, s2 = 0.f;
#pragma unroll
        for (int r = 0; r < 8; ++r) {
            s1 += sums[r * 128 + tid];
            s2 += sums[r * 128 + 64 + tid];
        }
        const float mu = s1 / (float)NN;
        const float ex2 = s2 / (float)NN;
        const float var = fmaxf(ex2 - mu * mu, 0.f);
        const float sc = gamma[tid] / sqrtf(var + BN_EPS);
        s_sc[tid] = sc;
        s_sh[tid] = beta[tid] - mu * sc;
    }
    __syncthreads();
    const int total = NN * OUT_C / 4;
    float4* p = (float4*)out;
    for (int idx = blockIdx.x * 256 + tid; idx < total; idx += gridDim.x * 256) {
        float4 v = p[idx];
        const int c0 = (idx & 15) * 4;
        v.x = fmaxf(fmaf(v.x, s_sc[c0 + 0], s_sh[c0 + 0]), 0.f);
        v.y = fmaxf(fmaf(v.y, s_sc[c0 + 1], s_sh[c0 + 1]), 0.f);
        v.z = fmaxf(fmaf(v.z, s_sc[c0 + 2], s_sh[c0 + 2]), 0.f);
        v.w = fmaxf(fmaf(v.w, s_sc[c0 + 3], s_sh[c0 + 3]), 0.f);
        p[idx] = v;
    }
}

extern "C" void kernel_launch(void* const* d_in, const int* in_sizes, int n_in,
                              void* d_out, int out_size, void* d_ws, size_t ws_size,
                              hipStream_t stream) {
    const float* x        = (const float*)d_in[0];
    const float* emb      = (const float*)d_in[1];
    const int*   edge     = (const int*)d_in[2];   // row 0 = src
    const float* lin_w    = (const float*)d_in[3];
    const float* att_i    = (const float*)d_in[4];
    const float* att_j    = (const float*)d_in[5];
    const float* att_em_i = (const float*)d_in[6];
    const float* att_em_j = (const float*)d_in[7];
    const float* bias     = (const float*)d_in[8];
    const float* gamma    = (const float*)d_in[9];
    const float* beta     = (const float*)d_in[10];

    float* ws    = (float*)d_ws;
    unsigned short* x_bf = (unsigned short*)(ws + WS_XBF);
    float* a_i   = ws + WS_AI;
    float* a_j   = ws + WS_AJ;
    float* sums  = ws + WS_SUMS;
    float* out   = (float*)d_out;

    k1_mfma<<<K1_BLOCKS, 256, 0, stream>>>(x, emb, lin_w, att_i, att_j,
                                           att_em_i, att_em_j, x_bf, a_i, a_j, sums);
    k2_attn<<<K2_BLOCKS, 64, 0, stream>>>(edge, (const uint4*)x_bf, a_j, a_i,
                                          bias, out, sums);
    k4_bn<<<1024, 256, 0, stream>>>(out, sums, gamma, beta);
}

// Round 4
// 288.171 us; speedup vs baseline: 1.1496x; 1.0121x over previous
//
#include <hip/hip_runtime.h>

#define NN 50000
#define TOPK 32
#define IN_C 128
#define OUT_C 64
#define NEG_SLOPE 0.2f
#define BN_EPS 1e-5f

// K1: MFMA, 16 nodes per block
#define K1_BLOCKS (NN / 16)         // 3125
// K2: 64-thread blocks, 1 wave = 8 nodes (8 lanes x 16B = full row)
#define K2_BLOCKS (NN / 8)          // 6250
#define STAGED 20                   // edges 0..19 staged in LDS (20 KB)

// workspace layout (floats)
#define WS_XBF   0                       // bf16 x_lin: NN*64*2B
#define WS_AI    (NN * 32)
#define WS_AJ    (WS_AI + NN)
#define WS_SUMS  (WS_AJ + NN)            // 8 replicas x 128

typedef __bf16 bf16x8 __attribute__((ext_vector_type(8)));
typedef float f32x4 __attribute__((ext_vector_type(4)));
union BF8 { unsigned p[4]; bf16x8 v; };

__device__ inline float leaky(float a) { return a >= 0.f ? a : NEG_SLOPE * a; }
__device__ inline float bl(unsigned u) { return __uint_as_float(u << 16); }
__device__ inline float bh(unsigned u) { return __uint_as_float(u & 0xffff0000u); }

// fp32 -> bf16 via compiler cast (lowers to v_cvt_pk_bf16_f32, RNE)
__device__ inline unsigned pk2bf(float lo, float hi) {
    union { __bf16 b[2]; unsigned u; } cv;
    cv.b[0] = (__bf16)lo; cv.b[1] = (__bf16)hi;
    return cv.u;
}
__device__ inline unsigned short f2bf(float f) {
    union { __bf16 b; unsigned short u; } cv;
    cv.b = (__bf16)f;
    return cv.u;
}

// async global->LDS, 16 B per lane; LDS dest = base + lane*16 (HW rule)
__device__ inline void async16(const uint4* g, uint4* l) {
    __builtin_amdgcn_global_load_lds(
        (const __attribute__((address_space(1))) void*)(const void*)g,
        (__attribute__((address_space(3))) void*)(void*)l, 16, 0, 0);
}

// K1: x_lin(bf16) = x @ lin_w^T via MFMA 16x16x32_bf16 + a_i/a_j epilogue.
__global__ __launch_bounds__(256) void k1_mfma(
    const float* __restrict__ x, const float* __restrict__ emb,
    const float* __restrict__ lin_w,
    const float* __restrict__ att_i, const float* __restrict__ att_j,
    const float* __restrict__ att_em_i, const float* __restrict__ att_em_j,
    unsigned short* __restrict__ x_bf, float* __restrict__ a_i,
    float* __restrict__ a_j, float* __restrict__ sums)
{
    __shared__ float redi[16][5], redj[16][5];
    __shared__ float eredi[16][17], eredj[16][17];
    const int tid = threadIdx.x;
    if (blockIdx.x == 0) {
#pragma unroll
        for (int i = 0; i < 4; ++i) sums[tid + i * 256] = 0.f;
    }

    const int lane = tid & 63;
    const int wv = tid >> 6;
    const int quad = lane >> 4;
    const int nn = lane & 15;
    const int base = blockIdx.x * 16;
    const int c = wv * 16 + nn;          // this lane's output channel

    BF8 bfr[4], afr[4];
    {
        const float* wr = lin_w + (size_t)c * IN_C + quad * 8;
        const float* xr = x + (size_t)(base + nn) * IN_C + quad * 8;
#pragma unroll
        for (int s = 0; s < 4; ++s) {
            const float4 wa = *(const float4*)(wr + s * 32);
            const float4 wb = *(const float4*)(wr + s * 32 + 4);
            const float4 xa = *(const float4*)(xr + s * 32);
            const float4 xb = *(const float4*)(xr + s * 32 + 4);
            bfr[s].p[0] = pk2bf(wa.x, wa.y);
            bfr[s].p[1] = pk2bf(wa.z, wa.w);
            bfr[s].p[2] = pk2bf(wb.x, wb.y);
            bfr[s].p[3] = pk2bf(wb.z, wb.w);
            afr[s].p[0] = pk2bf(xa.x, xa.y);
            afr[s].p[1] = pk2bf(xa.z, xa.w);
            afr[s].p[2] = pk2bf(xb.x, xb.y);
            afr[s].p[3] = pk2bf(xb.z, xb.w);
        }
    }

    f32x4 acc = {0.f, 0.f, 0.f, 0.f};
#pragma unroll
    for (int s = 0; s < 4; ++s)
        acc = __builtin_amdgcn_mfma_f32_16x16x32_bf16(afr[s].v, bfr[s].v, acc,
                                                      0, 0, 0);

    const float aic = att_i[c], ajc = att_j[c];
    float pi[4], pj[4];
#pragma unroll
    for (int r = 0; r < 4; ++r) {
        const int node = base + quad * 4 + r;
        x_bf[(size_t)node * OUT_C + c] = f2bf(acc[r]);
        pi[r] = acc[r] * aic;
        pj[r] = acc[r] * ajc;
    }
#pragma unroll
    for (int d = 1; d < 16; d <<= 1) {
#pragma unroll
        for (int r = 0; r < 4; ++r) {
            pi[r] += __shfl_xor(pi[r], d, 64);
            pj[r] += __shfl_xor(pj[r], d, 64);
        }
    }
    if (nn == 0) {
#pragma unroll
        for (int r = 0; r < 4; ++r) {
            redi[quad * 4 + r][wv] = pi[r];
            redj[quad * 4 + r][wv] = pj[r];
        }
    }
    {
        const int nl = tid >> 4, c4 = tid & 15;
        const float4 e4 = ((const float4*)emb)[(size_t)(base + nl) * 16 + c4];
        const float4 i4 = ((const float4*)att_em_i)[c4];
        const float4 j4 = ((const float4*)att_em_j)[c4];
        eredi[nl][c4] = e4.x * i4.x + e4.y * i4.y + e4.z * i4.z + e4.w * i4.w;
        eredj[nl][c4] = e4.x * j4.x + e4.y * j4.y + e4.z * j4.z + e4.w * j4.w;
    }
    __syncthreads();
    if (tid < 16) {
        float si = redi[tid][0] + redi[tid][1] + redi[tid][2] + redi[tid][3];
        float sj = redj[tid][0] + redj[tid][1] + redj[tid][2] + redj[tid][3];
#pragma unroll
        for (int r = 0; r < 16; ++r) { si += eredi[tid][r]; sj += eredj[tid][r]; }
        a_i[base + tid] = si;
        a_j[base + tid] = sj;
    }
}

// per-edge accumulate: row u (8 bf16 channels) * weight w into A[8]
__device__ inline void accr(float* A, const uint4 u, const float w) {
    A[0] = fmaf(w, bl(u.x), A[0]); A[1] = fmaf(w, bh(u.x), A[1]);
    A[2] = fmaf(w, bl(u.y), A[2]); A[3] = fmaf(w, bh(u.y), A[3]);
    A[4] = fmaf(w, bl(u.z), A[4]); A[5] = fmaf(w, bh(u.z), A[5]);
    A[6] = fmaf(w, bl(u.w), A[6]); A[7] = fmaf(w, bh(u.w), A[7]);
}

// K2 v5: R3 structure with the scratch bug fixed.
// R3 post-mortem: `sq = s4[q]` (runtime index into a register array) put
// s4[8] in scratch (rule #20) -> WRITE_SIZE 87.5 MB vs 13 MB ideal, scratch
// read on the softmax critical path. Fix: load sq directly from global
// (round-0 pattern; the cache line is L1-resident). s4[] now only ever
// indexed by compile-time constants -> stays in VGPRs.
__global__ __launch_bounds__(64) void k2_attn(
    const int* __restrict__ src, const uint4* __restrict__ x_bf4,
    const float* __restrict__ a_j, const float* __restrict__ a_i,
    const float* __restrict__ bias, float* __restrict__ out,
    float* __restrict__ sums)
{
    __shared__ uint4 stage[STAGED * 64];  // 20 KB staged rows

    const int tid = threadIdx.x;         // == lane (64-thread block)
    const int g = tid >> 3;              // node within group of 8
    const int q = tid & 7;               // row slice
    const int gb = tid & 56;             // g*8 = first lane of this group
    const int t = blockIdx.x * 8 + g;

    // all 32 src indices of this lane's node (broadcast across its 8 lanes)
    const int4* sp4 = (const int4*)(src + (size_t)t * TOPK);
    int4 s4[8];
#pragma unroll
    for (int i = 0; i < 8; ++i) s4[i] = sp4[i];
    const int4 sq = sp4[q];              // direct global load — NOT s4[q]

    // issue staged gathers: edge e=4i+c -> stage[e*64 + lane]
#pragma unroll
    for (int i = 0; i < STAGED / 4; ++i) {
        async16(x_bf4 + ((size_t)s4[i].x * 8 + q), &stage[(i * 4 + 0) * 64]);
        async16(x_bf4 + ((size_t)s4[i].y * 8 + q), &stage[(i * 4 + 1) * 64]);
        async16(x_bf4 + ((size_t)s4[i].z * 8 + q), &stage[(i * 4 + 2) * 64]);
        async16(x_bf4 + ((size_t)s4[i].w * 8 + q), &stage[(i * 4 + 3) * 64]);
    }

    // attention-logit inputs next (softmax overlaps in-flight gathers)
    const float ai_t = a_i[t];
    const float aj0 = a_j[sq.x], aj1 = a_j[sq.y];
    const float aj2 = a_j[sq.z], aj3 = a_j[sq.w];
    const float ajs = a_j[t];

    // register rows: edges 20..31 + self, issued upfront (issue-all pattern)
    uint4 r[12];
    r[0]  = x_bf4[(size_t)s4[5].x * 8 + q];
    r[1]  = x_bf4[(size_t)s4[5].y * 8 + q];
    r[2]  = x_bf4[(size_t)s4[5].z * 8 + q];
    r[3]  = x_bf4[(size_t)s4[5].w * 8 + q];
    r[4]  = x_bf4[(size_t)s4[6].x * 8 + q];
    r[5]  = x_bf4[(size_t)s4[6].y * 8 + q];
    r[6]  = x_bf4[(size_t)s4[6].z * 8 + q];
    r[7]  = x_bf4[(size_t)s4[6].w * 8 + q];
    r[8]  = x_bf4[(size_t)s4[7].x * 8 + q];
    r[9]  = x_bf4[(size_t)s4[7].y * 8 + q];
    r[10] = x_bf4[(size_t)s4[7].z * 8 + q];
    r[11] = x_bf4[(size_t)s4[7].w * 8 + q];
    const uint4 rs = x_bf4[(size_t)t * 8 + q];   // self row

    // softmax over 33 edges: lane q owns edges q*4..q*4+3
    float l0 = leaky(ai_t + aj0);
    float l1 = leaky(ai_t + aj1);
    float l2 = leaky(ai_t + aj2);
    float l3 = leaky(ai_t + aj3);
    const float ls = leaky(ai_t + ajs);
    float mx = fmaxf(fmaxf(l0, l1), fmaxf(l2, l3));
#pragma unroll
    for (int d = 1; d < 8; d <<= 1) mx = fmaxf(mx, __shfl_xor(mx, d, 64));
    mx = fmaxf(mx, ls);
    const float e0 = __expf(l0 - mx), e1 = __expf(l1 - mx);
    const float e2 = __expf(l2 - mx), e3 = __expf(l3 - mx);
    const float es = __expf(ls - mx);
    float den = (e0 + e1) + (e2 + e3);
#pragma unroll
    for (int d = 1; d < 8; d <<= 1) den += __shfl_xor(den, d, 64);
    den += es + 1e-16f;
    const float inv = 1.f / den;
    const float w0 = e0 * inv, w1 = e1 * inv, w2 = e2 * inv, w3 = e3 * inv;
    const float wself = es * inv;        // lane-uniform within group

    __builtin_amdgcn_s_waitcnt(0x0F70);  // vmcnt(0): staged + reg rows ready
    __syncthreads();

    float A[8];
#pragma unroll
    for (int j = 0; j < 8; ++j) A[j] = 0.f;

    // weight for edge 4b+k lives in lane gb+b's w{k}
#define WB(b) const float wx_ = __shfl(w0, gb + (b), 64);                   \
              const float wy_ = __shfl(w1, gb + (b), 64);                   \
              const float wz_ = __shfl(w2, gb + (b), 64);                   \
              const float ww_ = __shfl(w3, gb + (b), 64)

    // staged edges 0..19 (accumulation order preserved: e = 0..32)
#pragma unroll
    for (int b = 0; b < STAGED / 4; ++b) {
        WB(b);
        accr(A, stage[(b * 4 + 0) * 64 + tid], wx_);
        accr(A, stage[(b * 4 + 1) * 64 + tid], wy_);
        accr(A, stage[(b * 4 + 2) * 64 + tid], wz_);
        accr(A, stage[(b * 4 + 3) * 64 + tid], ww_);
    }
    // register edges 20..31
    { WB(5); accr(A, r[0], wx_); accr(A, r[1], wy_);
             accr(A, r[2], wz_); accr(A, r[3], ww_); }
    { WB(6); accr(A, r[4], wx_); accr(A, r[5], wy_);
             accr(A, r[6], wz_); accr(A, r[7], ww_); }
    { WB(7); accr(A, r[8], wx_); accr(A, r[9], wy_);
             accr(A, r[10], wz_); accr(A, r[11], ww_); }
    accr(A, rs, wself);                  // self loop
#undef WB

    const float4 b0 = ((const float4*)bias)[q * 2];
    const float4 b1 = ((const float4*)bias)[q * 2 + 1];
    float v[8];
    v[0] = A[0] + b0.x; v[1] = A[1] + b0.y; v[2] = A[2] + b0.z; v[3] = A[3] + b0.w;
    v[4] = A[4] + b1.x; v[5] = A[5] + b1.y; v[6] = A[6] + b1.z; v[7] = A[7] + b1.w;
    float4* o4 = (float4*)(out + (size_t)t * OUT_C + q * 8);
    o4[0] = make_float4(v[0], v[1], v[2], v[3]);
    o4[1] = make_float4(v[4], v[5], v[6], v[7]);

    // BN partials: reduce over the wave's 8 nodes (g axis = lane bits 3..5)
    float s1[8], s2[8];
#pragma unroll
    for (int j = 0; j < 8; ++j) { s1[j] = v[j]; s2[j] = v[j] * v[j]; }
#pragma unroll
    for (int d = 8; d < 64; d <<= 1) {
#pragma unroll
        for (int j = 0; j < 8; ++j) {
            s1[j] += __shfl_xor(s1[j], d, 64);
            s2[j] += __shfl_xor(s2[j], d, 64);
        }
    }
    if (tid < 8) {                       // lane q=tid holds channels tid*8+j
        float* rep = sums + (blockIdx.x & 7) * 128;
#pragma unroll
        for (int j = 0; j < 8; ++j) {
            atomicAdd(&rep[tid * 8 + j], s1[j]);
            atomicAdd(&rep[64 + tid * 8 + j], s2[j]);
        }
    }
}

// K4: BN stats from the 8 sum replicas (redundant per block), apply + ReLU.
__global__ __launch_bounds__(256) void k4_bn(
    float* __restrict__ out, const float* __restrict__ sums,
    const float* __restrict__ gamma, const float* __restrict__ beta)
{
    __shared__ float s_sc[64], s_sh[64];
    const int tid = threadIdx.x;
    if (tid < 64) {
        float s1 = 0.f, s2 = 0.f;
#pragma unroll
        for (int r = 0; r < 8; ++r) {
            s1 += sums[r * 128 + tid];
            s2 += sums[r * 128 + 64 + tid];
        }
        const float mu = s1 / (float)NN;
        const float ex2 = s2 / (float)NN;
        const float var = fmaxf(ex2 - mu * mu, 0.f);
        const float sc = gamma[tid] / sqrtf(var + BN_EPS);
        s_sc[tid] = sc;
        s_sh[tid] = beta[tid] - mu * sc;
    }
    __syncthreads();
    const int total = NN * OUT_C / 4;
    float4* p = (float4*)out;
    for (int idx = blockIdx.x * 256 + tid; idx < total; idx += gridDim.x * 256) {
        float4 v = p[idx];
        const int c0 = (idx & 15) * 4;
        v.x = fmaxf(fmaf(v.x, s_sc[c0 + 0], s_sh[c0 + 0]), 0.f);
        v.y = fmaxf(fmaf(v.y, s_sc[c0 + 1], s_sh[c0 + 1]), 0.f);
        v.z = fmaxf(fmaf(v.z, s_sc[c0 + 2], s_sh[c0 + 2]), 0.f);
        v.w = fmaxf(fmaf(v.w, s_sc[c0 + 3], s_sh[c0 + 3]), 0.f);
        p[idx] = v;
    }
}

extern "C" void kernel_launch(void* const* d_in, const int* in_sizes, int n_in,
                              void* d_out, int out_size, void* d_ws, size_t ws_size,
                              hipStream_t stream) {
    const float* x        = (const float*)d_in[0];
    const float* emb      = (const float*)d_in[1];
    const int*   edge     = (const int*)d_in[2];   // row 0 = src
    const float* lin_w    = (const float*)d_in[3];
    const float* att_i    = (const float*)d_in[4];
    const float* att_j    = (const float*)d_in[5];
    const float* att_em_i = (const float*)d_in[6];
    const float* att_em_j = (const float*)d_in[7];
    const float* bias     = (const float*)d_in[8];
    const float* gamma    = (const float*)d_in[9];
    const float* beta     = (const float*)d_in[10];

    float* ws    = (float*)d_ws;
    unsigned short* x_bf = (unsigned short*)(ws + WS_XBF);
    float* a_i   = ws + WS_AI;
    float* a_j   = ws + WS_AJ;
    float* sums  = ws + WS_SUMS;
    float* out   = (float*)d_out;

    k1_mfma<<<K1_BLOCKS, 256, 0, stream>>>(x, emb, lin_w, att_i, att_j,
                                           att_em_i, att_em_j, x_bf, a_i, a_j, sums);
    k2_attn<<<K2_BLOCKS, 64, 0, stream>>>(edge, (const uint4*)x_bf, a_j, a_i,
                                          bias, out, sums);
    k4_bn<<<1024, 256, 0, stream>>>(out, sums, gamma, beta);
}